// Round 1
// baseline (78.702 us; speedup 1.0000x reference)
//
#include <hip/hip_runtime.h>

// Elementwise fuzzify: y[r, i] = clip(diag[r] * aug_r(x[i]) + b[r], 0, 1)
// for r in 0..8.  Pure memory-bound map: 4 B read + 36 B write per element.

__global__ __launch_bounds__(256) void fuzzify_kernel(
    const float* __restrict__ x,
    const float* __restrict__ p_td_c,
    const float* __restrict__ p_td_s,
    const float* __restrict__ p_dl_s,
    const float* __restrict__ p_dl_cw,
    const float* __restrict__ p_dl_sw,
    const float* __restrict__ p_dl_ssw,
    float* __restrict__ out, int n)
{
    const float ms = 0.01f;
    const float td_c = p_td_c[0];
    const float td_s = fabsf(p_td_s[0] - ms) + ms;
    const float dl_s = fabsf(p_dl_s[0] - ms) + ms;

    const float slope_width = 1.0f / dl_s;
    const float cw  = fabsf(p_dl_cw[0]);
    const float sw  = fabsf(p_dl_sw[0]);
    const float ssw = fabsf(p_dl_ssw[0]);
    const float c_half  = 0.5f * cw;
    const float s_half  = 0.5f * sw;
    const float ss_half = 0.5f * ssw;

    const float d1 = dl_s * s_half + 1.0f;
    const float c1 = c_half + slope_width + s_half;
    const float d2 = dl_s * ss_half + 1.0f;
    const float c2 = c_half + 2.0f * slope_width + sw + ss_half;
    const float c3 = c_half + sw + 3.0f * slope_width + ssw;
    const float d3 = -dl_s * c3 + 1.0f;
    const float a  = td_c * td_s;

    const float diag[9] = { -td_s, td_s, dl_s, -dl_s, -dl_s, -dl_s, -dl_s, -dl_s, dl_s };
    const float bias[9] = { 1.0f + a, -a, d3, d2, d1, dl_s * c_half + 1.0f, d1, d2, d3 };

    const int n4 = n >> 2;  // n is 2^23, divisible by 4
    const float4* __restrict__ x4 = (const float4*)x;
    const int stride = gridDim.x * blockDim.x;

    for (int i = blockIdx.x * blockDim.x + threadIdx.x; i < n4; i += stride) {
        float4 v = x4[i];
        float xv[4] = { v.x, v.y, v.z, v.w };

        #pragma unroll
        for (int r = 0; r < 9; ++r) {
            float4 o;
            float* op = &o.x;
            #pragma unroll
            for (int j = 0; j < 4; ++j) {
                float xx = xv[j];
                float aug;
                if      (r == 0 || r == 1 || r == 8) aug = xx;
                else if (r == 2) aug = -xx;
                else if (r == 3) aug = fabsf(xx + c2);
                else if (r == 4) aug = fabsf(xx + c1);
                else if (r == 5) aug = fabsf(xx);
                else if (r == 6) aug = fabsf(xx - c1);
                else             aug = fabsf(xx - c2);
                float y = diag[r] * aug + bias[r];
                op[j] = fminf(fmaxf(y, 0.0f), 1.0f);  // v_med3_f32
            }
            *(float4*)(out + (size_t)r * (size_t)n + ((size_t)i << 2)) = o;
        }
    }
}

extern "C" void kernel_launch(void* const* d_in, const int* in_sizes, int n_in,
                              void* d_out, int out_size, void* d_ws, size_t ws_size,
                              hipStream_t stream) {
    const float* x        = (const float*)d_in[0];
    const float* p_td_c   = (const float*)d_in[1];
    const float* p_td_s   = (const float*)d_in[2];
    const float* p_dl_s   = (const float*)d_in[3];
    const float* p_dl_cw  = (const float*)d_in[4];
    const float* p_dl_sw  = (const float*)d_in[5];
    const float* p_dl_ssw = (const float*)d_in[6];
    float* out = (float*)d_out;

    const int n = in_sizes[0];
    const int block = 256;
    const int grid = 2048;  // grid-stride; 8M/4 elems / (2048*256) = 4 iters/thread

    fuzzify_kernel<<<grid, block, 0, stream>>>(
        x, p_td_c, p_td_s, p_dl_s, p_dl_cw, p_dl_sw, p_dl_ssw, out, n);
}

// Round 3
// 73.931 us; speedup vs baseline: 1.0645x; 1.0645x over previous
//
#include <hip/hip_runtime.h>

// Elementwise fuzzify: y[r, i] = clip(diag[r] * aug_r(x[i]) + b[r], 0, 1)
// for r in 0..8.  Memory-bound map: 4 B read + 36 B write per element.
// R3: nontemporal loads/stores via clang ext_vector_type (HIP_vector_type
// structs are rejected by the builtin). Output (302 MB) is write-once
// streaming > 256 MB LLC; bypass cache to avoid write-allocate churn.

typedef float f32x4 __attribute__((ext_vector_type(4)));

__global__ __launch_bounds__(256) void fuzzify_kernel(
    const float* __restrict__ x,
    const float* __restrict__ p_td_c,
    const float* __restrict__ p_td_s,
    const float* __restrict__ p_dl_s,
    const float* __restrict__ p_dl_cw,
    const float* __restrict__ p_dl_sw,
    const float* __restrict__ p_dl_ssw,
    float* __restrict__ out, int n)
{
    const float ms = 0.01f;
    const float td_c = p_td_c[0];
    const float td_s = fabsf(p_td_s[0] - ms) + ms;
    const float dl_s = fabsf(p_dl_s[0] - ms) + ms;

    const float slope_width = 1.0f / dl_s;
    const float cw  = fabsf(p_dl_cw[0]);
    const float sw  = fabsf(p_dl_sw[0]);
    const float ssw = fabsf(p_dl_ssw[0]);
    const float c_half  = 0.5f * cw;
    const float s_half  = 0.5f * sw;
    const float ss_half = 0.5f * ssw;

    const float d1 = dl_s * s_half + 1.0f;
    const float c1 = c_half + slope_width + s_half;
    const float d2 = dl_s * ss_half + 1.0f;
    const float c2 = c_half + 2.0f * slope_width + sw + ss_half;
    const float c3 = c_half + sw + 3.0f * slope_width + ssw;
    const float d3 = -dl_s * c3 + 1.0f;
    const float a  = td_c * td_s;

    const float diag[9] = { -td_s, td_s, dl_s, -dl_s, -dl_s, -dl_s, -dl_s, -dl_s, dl_s };
    const float bias[9] = { 1.0f + a, -a, d3, d2, d1, dl_s * c_half + 1.0f, d1, d2, d3 };

    const int n4 = n >> 2;  // n is 2^23, divisible by 4
    const f32x4* __restrict__ x4 = (const f32x4*)x;
    const int stride = gridDim.x * blockDim.x;

    for (int i = blockIdx.x * blockDim.x + threadIdx.x; i < n4; i += stride) {
        f32x4 v = __builtin_nontemporal_load(&x4[i]);
        float xv[4] = { v.x, v.y, v.z, v.w };

        #pragma unroll
        for (int r = 0; r < 9; ++r) {
            f32x4 o;
            #pragma unroll
            for (int j = 0; j < 4; ++j) {
                float xx = xv[j];
                float aug;
                if      (r == 0 || r == 1 || r == 8) aug = xx;
                else if (r == 2) aug = -xx;
                else if (r == 3) aug = fabsf(xx + c2);
                else if (r == 4) aug = fabsf(xx + c1);
                else if (r == 5) aug = fabsf(xx);
                else if (r == 6) aug = fabsf(xx - c1);
                else             aug = fabsf(xx - c2);
                float y = diag[r] * aug + bias[r];
                o[j] = fminf(fmaxf(y, 0.0f), 1.0f);  // v_med3_f32
            }
            f32x4* dst = (f32x4*)(out + (size_t)r * (size_t)n + ((size_t)i << 2));
            __builtin_nontemporal_store(o, dst);
        }
    }
}

extern "C" void kernel_launch(void* const* d_in, const int* in_sizes, int n_in,
                              void* d_out, int out_size, void* d_ws, size_t ws_size,
                              hipStream_t stream) {
    const float* x        = (const float*)d_in[0];
    const float* p_td_c   = (const float*)d_in[1];
    const float* p_td_s   = (const float*)d_in[2];
    const float* p_dl_s   = (const float*)d_in[3];
    const float* p_dl_cw  = (const float*)d_in[4];
    const float* p_dl_sw  = (const float*)d_in[5];
    const float* p_dl_ssw = (const float*)d_in[6];
    float* out = (float*)d_out;

    const int n = in_sizes[0];
    const int block = 256;
    const int grid = 2048;  // 2048*256 threads, 4 float4-iters each; 32 waves/CU

    fuzzify_kernel<<<grid, block, 0, stream>>>(
        x, p_td_c, p_td_s, p_dl_s, p_dl_cw, p_dl_sw, p_dl_ssw, out, n);
}